// Round 1
// baseline (6798.941 us; speedup 1.0000x reference)
//
#include <hip/hip_runtime.h>
#include <math.h>

#define NB 4
#define SS 2048
#define NTOK (NB*SS)      // 8192
#define DD 1024
#define HH 512
#define EE 8
#define FF 2816
#define RR 16
#define HID 128
#define NSLOT (2*NTOK)    // 16384
#define LN_EPS 1e-5f

// ------------------------------------------------------------------
// K0a: c[d] = ln_g[d]*Wg[d]; scal[0]=sum(c); scal[1]=sum(ln_b*Wg)+bg
// ------------------------------------------------------------------
__global__ void k_prec(const float* __restrict__ ln_g, const float* __restrict__ ln_b,
                       const float* __restrict__ Wg, const float* __restrict__ bg,
                       float* __restrict__ cvec, float* __restrict__ scal) {
  __shared__ float red0[256], red1[256];
  int tid = threadIdx.x;
  float s0 = 0.f, s1 = 0.f;
  for (int d = tid; d < DD; d += 256) {
    float w = Wg[d];
    float cv = ln_g[d] * w;
    cvec[d] = cv;
    s0 += cv;
    s1 += ln_b[d] * w;
  }
  red0[tid] = s0; red1[tid] = s1;
  __syncthreads();
  for (int off = 128; off > 0; off >>= 1) {
    if (tid < off) { red0[tid] += red0[tid+off]; red1[tid] += red1[tid+off]; }
    __syncthreads();
  }
  if (tid == 0) { scal[0] = red0[0]; scal[1] = red1[0] + bg[0]; }
}

// ------------------------------------------------------------------
// K0b: pp[e][k] = persona[e]@W1p[:,k] + b1[k]   (blocks 0..7)
//      hp[b][k] = hist[b]@W1h[:,k]              (blocks 8..11)
// ------------------------------------------------------------------
__global__ void k_proj_small(const float* __restrict__ hist, const float* __restrict__ persona,
                             const float* __restrict__ W1h, const float* __restrict__ W1p,
                             const float* __restrict__ b1,
                             float* __restrict__ hp, float* __restrict__ pp) {
  int blk = blockIdx.x, k = threadIdx.x;   // 128 threads
  if (blk < EE) {
    int e = blk;
    float acc = b1[k];
    for (int d = 0; d < DD; ++d) acc += persona[e*DD + d] * W1p[d*HID + k];
    pp[e*HID + k] = acc;
  } else {
    int b = blk - EE;
    float acc = 0.f;
    for (int d = 0; d < HH; ++d) acc += hist[b*HH + d] * W1h[d*HID + k];
    hp[b*HID + k] = acc;
  }
}

// ------------------------------------------------------------------
// K1: xp[N,128] = x[N,1024] @ W1x[1024,128]   (128x128 tile, BK=16)
// ------------------------------------------------------------------
__global__ __launch_bounds__(256) void k_xp(const float* __restrict__ x,
                                            const float* __restrict__ W1x,
                                            float* __restrict__ xp) {
  __shared__ float As[16][128];
  __shared__ float Bs[16][128];
  const int tid = threadIdx.x;
  const int r0 = blockIdx.x * 128;
  const int ty = tid >> 4, tx = tid & 15;
  const int cA = tid * 2;
  const int ar0 = cA >> 2, ak0 = (cA & 3) * 4;
  const int ar1 = (cA+1) >> 2, ak1 = ((cA+1) & 3) * 4;
  const int bk0 = cA >> 5, bc0 = (cA & 31) * 4;
  const int bk1 = (cA+1) >> 5, bc1 = ((cA+1) & 31) * 4;
  float acc[8][8] = {};
  for (int k0 = 0; k0 < DD; k0 += 16) {
    float4 av0 = *(const float4*)&x[(size_t)(r0+ar0)*DD + k0 + ak0];
    float4 av1 = *(const float4*)&x[(size_t)(r0+ar1)*DD + k0 + ak1];
    float4 bv0 = *(const float4*)&W1x[(size_t)(k0+bk0)*HID + bc0];
    float4 bv1 = *(const float4*)&W1x[(size_t)(k0+bk1)*HID + bc1];
    __syncthreads();
    As[ak0+0][ar0]=av0.x; As[ak0+1][ar0]=av0.y; As[ak0+2][ar0]=av0.z; As[ak0+3][ar0]=av0.w;
    As[ak1+0][ar1]=av1.x; As[ak1+1][ar1]=av1.y; As[ak1+2][ar1]=av1.z; As[ak1+3][ar1]=av1.w;
    *(float4*)&Bs[bk0][bc0] = bv0;
    *(float4*)&Bs[bk1][bc1] = bv1;
    __syncthreads();
#pragma unroll
    for (int kk = 0; kk < 16; ++kk) {
      float4 a0 = *(const float4*)&As[kk][ty*8];
      float4 a1 = *(const float4*)&As[kk][ty*8+4];
      float4 b0 = *(const float4*)&Bs[kk][tx*8];
      float4 b1v= *(const float4*)&Bs[kk][tx*8+4];
      float a[8] = {a0.x,a0.y,a0.z,a0.w,a1.x,a1.y,a1.z,a1.w};
      float b[8] = {b0.x,b0.y,b0.z,b0.w,b1v.x,b1v.y,b1v.z,b1v.w};
#pragma unroll
      for (int i = 0; i < 8; ++i)
#pragma unroll
        for (int j = 0; j < 8; ++j) acc[i][j] += a[i]*b[j];
    }
  }
#pragma unroll
  for (int i = 0; i < 8; ++i) {
    float* op = xp + (size_t)(r0 + ty*8 + i)*HID + tx*8;
    *(float4*)&op[0] = make_float4(acc[i][0],acc[i][1],acc[i][2],acc[i][3]);
    *(float4*)&op[4] = make_float4(acc[i][4],acc[i][5],acc[i][6],acc[i][7]);
  }
}

// ------------------------------------------------------------------
// K2: gating. One block per token: h1[e][k]=relu(xp+hp+pp); reduce
// f=relu(h1@W2+b2) against (1, f, c) -> logits -> softmax -> top2 ->
// scatter slots into per-expert lists.
// ------------------------------------------------------------------
__global__ __launch_bounds__(256) void k_gate(const float* __restrict__ xp,
    const float* __restrict__ hp, const float* __restrict__ pp,
    const float* __restrict__ W2, const float* __restrict__ b2,
    const float* __restrict__ cvec, const float* __restrict__ scal,
    float* __restrict__ wsel, int* __restrict__ eid,
    int* __restrict__ perm, int* __restrict__ cnt) {
  __shared__ float h1s[EE*HID];
  __shared__ float red[4][EE][3];
  const int t = blockIdx.x;
  const int b = t / SS;
  const int tid = threadIdx.x;
  const int lane = tid & 63, wave = tid >> 6;

  for (int idx = tid; idx < EE*HID; idx += 256) {
    int k = idx & (HID-1);
    float v = xp[(size_t)t*HID + k] + hp[b*HID + k] + pp[idx];
    h1s[idx] = v > 0.f ? v : 0.f;
  }
  __syncthreads();

  const int d4 = tid * 4;
  float acc[EE][4] = {};
  for (int k0 = 0; k0 < HID; k0 += 4) {
    float4 w0 = *(const float4*)&W2[(size_t)(k0+0)*DD + d4];
    float4 w1 = *(const float4*)&W2[(size_t)(k0+1)*DD + d4];
    float4 w2 = *(const float4*)&W2[(size_t)(k0+2)*DD + d4];
    float4 w3 = *(const float4*)&W2[(size_t)(k0+3)*DD + d4];
#pragma unroll
    for (int e = 0; e < EE; ++e) {
      float4 h = *(const float4*)&h1s[e*HID + k0];
      acc[e][0] += h.x*w0.x + h.y*w1.x + h.z*w2.x + h.w*w3.x;
      acc[e][1] += h.x*w0.y + h.y*w1.y + h.z*w2.y + h.w*w3.y;
      acc[e][2] += h.x*w0.z + h.y*w1.z + h.z*w2.z + h.w*w3.z;
      acc[e][3] += h.x*w0.w + h.y*w1.w + h.z*w2.w + h.w*w3.w;
    }
  }

  float4 b2v = *(const float4*)&b2[d4];
  float4 cv  = *(const float4*)&cvec[d4];
  float bb[4] = {b2v.x,b2v.y,b2v.z,b2v.w};
  float cc[4] = {cv.x,cv.y,cv.z,cv.w};
#pragma unroll
  for (int e = 0; e < EE; ++e) {
    float t0=0.f, t1=0.f, t2=0.f;
#pragma unroll
    for (int q = 0; q < 4; ++q) {
      float f = acc[e][q] + bb[q];
      f = f > 0.f ? f : 0.f;
      t0 += f; t1 += f*f; t2 += f*cc[q];
    }
#pragma unroll
    for (int off = 32; off > 0; off >>= 1) {
      t0 += __shfl_xor(t0, off);
      t1 += __shfl_xor(t1, off);
      t2 += __shfl_xor(t2, off);
    }
    if (lane == 0) { red[wave][e][0]=t0; red[wave][e][1]=t1; red[wave][e][2]=t2; }
  }
  __syncthreads();

  if (tid == 0) {
    float Scsum = scal[0], Cb = scal[1];
    float logits[EE];
#pragma unroll
    for (int e = 0; e < EE; ++e) {
      float s0 = red[0][e][0]+red[1][e][0]+red[2][e][0]+red[3][e][0];
      float s1 = red[0][e][1]+red[1][e][1]+red[2][e][1]+red[3][e][1];
      float sc = red[0][e][2]+red[1][e][2]+red[2][e][2]+red[3][e][2];
      float mu = s0 * (1.f/DD);
      float var = s1 * (1.f/DD) - mu*mu;
      float rs = rsqrtf(var + LN_EPS);
      logits[e] = rs * (sc - mu*Scsum) + Cb;
    }
    float m = logits[0];
#pragma unroll
    for (int e = 1; e < EE; ++e) m = fmaxf(m, logits[e]);
    float p[EE]; float sum = 0.f;
#pragma unroll
    for (int e = 0; e < EE; ++e) { p[e] = expf(logits[e]-m); sum += p[e]; }
    float inv = 1.f / sum;
    int i1 = 0;
    for (int e = 1; e < EE; ++e) if (p[e] > p[i1]) i1 = e;
    int i2 = (i1 == 0) ? 1 : 0;
    for (int e = 0; e < EE; ++e) if (e != i1 && p[e] > p[i2]) i2 = e;
    float w1 = p[i1]*inv, w2 = p[i2]*inv;
    wsel[2*t]   = w1;  wsel[2*t+1] = w2;
    eid[2*t]    = i1;  eid[2*t+1]  = i2;
    int pos = atomicAdd(&cnt[i1], 1); perm[i1*NTOK + pos] = 2*t;
    pos     = atomicAdd(&cnt[i2], 1); perm[i2*NTOK + pos] = 2*t+1;
  }
}

// ------------------------------------------------------------------
// K3: Pg/Pu[s,r] = x[token] @ Ag/Au[e][:,r]   (1 wave per slot)
// ------------------------------------------------------------------
__global__ __launch_bounds__(64) void k_lora_gu(const float* __restrict__ x,
    const float* __restrict__ Ag, const float* __restrict__ Au,
    const int* __restrict__ eid, float* __restrict__ Pg, float* __restrict__ Pu) {
  const int s = blockIdx.x, lane = threadIdx.x;
  const int e = eid[s];
  const int token = s >> 1;
  const int r = lane & 15, d0 = lane >> 4;
  const float* xr  = x  + (size_t)token*DD;
  const float* AgE = Ag + (size_t)e*DD*RR + r;
  const float* AuE = Au + (size_t)e*DD*RR + r;
  float g0=0.f, g1=0.f, u0=0.f, u1=0.f;
  for (int d = d0; d < DD; d += 8) {
    float x0 = xr[d], x1 = xr[d+4];
    g0 += x0 * AgE[(size_t)d*RR];     g1 += x1 * AgE[(size_t)(d+4)*RR];
    u0 += x0 * AuE[(size_t)d*RR];     u1 += x1 * AuE[(size_t)(d+4)*RR];
  }
  float g = g0+g1, u = u0+u1;
  g += __shfl_xor(g, 16); g += __shfl_xor(g, 32);
  u += __shfl_xor(u, 16); u += __shfl_xor(u, 32);
  if (lane < 16) { Pg[(size_t)s*RR + r] = g; Pu[(size_t)s*RR + r] = u; }
}

// ------------------------------------------------------------------
// K5: Pd[s,r] = H[s] @ Ad[e][:,r]
// ------------------------------------------------------------------
__global__ __launch_bounds__(64) void k_lora_d(const float* __restrict__ Hbuf,
    const float* __restrict__ Ad, const int* __restrict__ eid, float* __restrict__ Pd) {
  const int s = blockIdx.x, lane = threadIdx.x;
  const int e = eid[s];
  const int r = lane & 15, d0 = lane >> 4;
  const float* Hr  = Hbuf + (size_t)s*FF;
  const float* AdE = Ad + (size_t)e*FF*RR + r;
  float a0=0.f, a1=0.f;
  for (int d = d0; d < FF; d += 8) {
    a0 += Hr[d]   * AdE[(size_t)d*RR];
    a1 += Hr[d+4] * AdE[(size_t)(d+4)*RR];
  }
  float a = a0+a1;
  a += __shfl_xor(a, 16); a += __shfl_xor(a, 32);
  if (lane < 16) Pd[(size_t)s*RR + r] = a;
}

// ------------------------------------------------------------------
// K4a: Hbuf[s] = silu(x@Wgate[e] + Pg@Bg[e])  (rows gathered via perm)
// ------------------------------------------------------------------
__global__ __launch_bounds__(256) void k_gemm_g(
    const float* __restrict__ x, const float* __restrict__ Wgate,
    const float* __restrict__ BgW, const float* __restrict__ Pg,
    const int* __restrict__ perm, const int* __restrict__ cnt,
    float* __restrict__ Hbuf) {
  const int e = blockIdx.z;
  const int m = cnt[e];
  const int r0 = blockIdx.y * 128;
  if (r0 >= m) return;
  const int c0 = blockIdx.x * 128;

  __shared__ float As[16][128];
  __shared__ float Bs[16][128];
  __shared__ int slotArr[128];
  __shared__ int tokArr[128];

  const int tid = threadIdx.x;
  if (tid < 128) {
    int i = r0 + tid;
    int s = (i < m) ? perm[e*NTOK + i] : -1;
    slotArr[tid] = s;
    tokArr[tid]  = (s >= 0) ? (s >> 1) : 0;
  }
  __syncthreads();

  const int ty = tid >> 4, tx = tid & 15;
  const int cA = tid * 2;
  const int ar0 = cA >> 2, ak0 = (cA & 3) * 4;
  const int ar1 = (cA+1) >> 2, ak1 = ((cA+1) & 3) * 4;
  const int bk0 = cA >> 5, bc0 = (cA & 31) * 4;
  const int bk1 = (cA+1) >> 5, bc1 = ((cA+1) & 31) * 4;
  const float* Bp = Wgate + (size_t)e*DD*FF + c0;

  float acc[8][8] = {};
  for (int k0 = 0; k0 < DD; k0 += 16) {
    float4 av0 = *(const float4*)&x[(size_t)tokArr[ar0]*DD + k0 + ak0];
    float4 av1 = *(const float4*)&x[(size_t)tokArr[ar1]*DD + k0 + ak1];
    float4 bv0 = *(const float4*)&Bp[(size_t)(k0+bk0)*FF + bc0];
    float4 bv1 = *(const float4*)&Bp[(size_t)(k0+bk1)*FF + bc1];
    __syncthreads();
    As[ak0+0][ar0]=av0.x; As[ak0+1][ar0]=av0.y; As[ak0+2][ar0]=av0.z; As[ak0+3][ar0]=av0.w;
    As[ak1+0][ar1]=av1.x; As[ak1+1][ar1]=av1.y; As[ak1+2][ar1]=av1.z; As[ak1+3][ar1]=av1.w;
    *(float4*)&Bs[bk0][bc0] = bv0;
    *(float4*)&Bs[bk1][bc1] = bv1;
    __syncthreads();
#pragma unroll
    for (int kk = 0; kk < 16; ++kk) {
      float4 a0 = *(const float4*)&As[kk][ty*8];
      float4 a1 = *(const float4*)&As[kk][ty*8+4];
      float4 b0 = *(const float4*)&Bs[kk][tx*8];
      float4 b1v= *(const float4*)&Bs[kk][tx*8+4];
      float a[8] = {a0.x,a0.y,a0.z,a0.w,a1.x,a1.y,a1.z,a1.w};
      float b[8] = {b0.x,b0.y,b0.z,b0.w,b1v.x,b1v.y,b1v.z,b1v.w};
#pragma unroll
      for (int i = 0; i < 8; ++i)
#pragma unroll
        for (int j = 0; j < 8; ++j) acc[i][j] += a[i]*b[j];
    }
  }

  int srow[8];
#pragma unroll
  for (int i = 0; i < 8; ++i) srow[i] = slotArr[ty*8 + i];

  const float* BgE = BgW + (size_t)e*RR*FF + c0;
#pragma unroll
  for (int r = 0; r < RR; ++r) {
    float4 g0 = *(const float4*)&BgE[(size_t)r*FF + tx*8];
    float4 g1 = *(const float4*)&BgE[(size_t)r*FF + tx*8+4];
    float b[8] = {g0.x,g0.y,g0.z,g0.w,g1.x,g1.y,g1.z,g1.w};
#pragma unroll
    for (int i = 0; i < 8; ++i) {
      int s = srow[i];
      float pv = (s >= 0) ? Pg[(size_t)s*RR + r] : 0.f;
#pragma unroll
      for (int j = 0; j < 8; ++j) acc[i][j] += pv * b[j];
    }
  }

#pragma unroll
  for (int i = 0; i < 8; ++i) {
    int s = srow[i];
    if (s < 0) continue;
    float* Hr = Hbuf + (size_t)s*FF + c0 + tx*8;
    float v[8];
#pragma unroll
    for (int j = 0; j < 8; ++j) {
      float g = acc[i][j];
      v[j] = g / (1.f + expf(-g));
    }
    *(float4*)&Hr[0] = make_float4(v[0],v[1],v[2],v[3]);
    *(float4*)&Hr[4] = make_float4(v[4],v[5],v[6],v[7]);
  }
}

// ------------------------------------------------------------------
// K4b: Hbuf[s] = Hbuf[s] * (x@Wup[e] + Pu@Bu[e])
// ------------------------------------------------------------------
__global__ __launch_bounds__(256) void k_gemm_u(
    const float* __restrict__ x, const float* __restrict__ Wup,
    const float* __restrict__ BuW, const float* __restrict__ Pu,
    const int* __restrict__ perm, const int* __restrict__ cnt,
    float* __restrict__ Hbuf) {
  const int e = blockIdx.z;
  const int m = cnt[e];
  const int r0 = blockIdx.y * 128;
  if (r0 >= m) return;
  const int c0 = blockIdx.x * 128;

  __shared__ float As[16][128];
  __shared__ float Bs[16][128];
  __shared__ int slotArr[128];
  __shared__ int tokArr[128];

  const int tid = threadIdx.x;
  if (tid < 128) {
    int i = r0 + tid;
    int s = (i < m) ? perm[e*NTOK + i] : -1;
    slotArr[tid] = s;
    tokArr[tid]  = (s >= 0) ? (s >> 1) : 0;
  }
  __syncthreads();

  const int ty = tid >> 4, tx = tid & 15;
  const int cA = tid * 2;
  const int ar0 = cA >> 2, ak0 = (cA & 3) * 4;
  const int ar1 = (cA+1) >> 2, ak1 = ((cA+1) & 3) * 4;
  const int bk0 = cA >> 5, bc0 = (cA & 31) * 4;
  const int bk1 = (cA+1) >> 5, bc1 = ((cA+1) & 31) * 4;
  const float* Bp = Wup + (size_t)e*DD*FF + c0;

  float acc[8][8] = {};
  for (int k0 = 0; k0 < DD; k0 += 16) {
    float4 av0 = *(const float4*)&x[(size_t)tokArr[ar0]*DD + k0 + ak0];
    float4 av1 = *(const float4*)&x[(size_t)tokArr[ar1]*DD + k0 + ak1];
    float4 bv0 = *(const float4*)&Bp[(size_t)(k0+bk0)*FF + bc0];
    float4 bv1 = *(const float4*)&Bp[(size_t)(k0+bk1)*FF + bc1];
    __syncthreads();
    As[ak0+0][ar0]=av0.x; As[ak0+1][ar0]=av0.y; As[ak0+2][ar0]=av0.z; As[ak0+3][ar0]=av0.w;
    As[ak1+0][ar1]=av1.x; As[ak1+1][ar1]=av1.y; As[ak1+2][ar1]=av1.z; As[ak1+3][ar1]=av1.w;
    *(float4*)&Bs[bk0][bc0] = bv0;
    *(float4*)&Bs[bk1][bc1] = bv1;
    __syncthreads();
#pragma unroll
    for (int kk = 0; kk < 16; ++kk) {
      float4 a0 = *(const float4*)&As[kk][ty*8];
      float4 a1 = *(const float4*)&As[kk][ty*8+4];
      float4 b0 = *(const float4*)&Bs[kk][tx*8];
      float4 b1v= *(const float4*)&Bs[kk][tx*8+4];
      float a[8] = {a0.x,a0.y,a0.z,a0.w,a1.x,a1.y,a1.z,a1.w};
      float b[8] = {b0.x,b0.y,b0.z,b0.w,b1v.x,b1v.y,b1v.z,b1v.w};
#pragma unroll
      for (int i = 0; i < 8; ++i)
#pragma unroll
        for (int j = 0; j < 8; ++j) acc[i][j] += a[i]*b[j];
    }
  }

  int srow[8];
#pragma unroll
  for (int i = 0; i < 8; ++i) srow[i] = slotArr[ty*8 + i];

  const float* BuE = BuW + (size_t)e*RR*FF + c0;
#pragma unroll
  for (int r = 0; r < RR; ++r) {
    float4 g0 = *(const float4*)&BuE[(size_t)r*FF + tx*8];
    float4 g1 = *(const float4*)&BuE[(size_t)r*FF + tx*8+4];
    float b[8] = {g0.x,g0.y,g0.z,g0.w,g1.x,g1.y,g1.z,g1.w};
#pragma unroll
    for (int i = 0; i < 8; ++i) {
      int s = srow[i];
      float pv = (s >= 0) ? Pu[(size_t)s*RR + r] : 0.f;
#pragma unroll
      for (int j = 0; j < 8; ++j) acc[i][j] += pv * b[j];
    }
  }

#pragma unroll
  for (int i = 0; i < 8; ++i) {
    int s = srow[i];
    if (s < 0) continue;
    float* Hr = Hbuf + (size_t)s*FF + c0 + tx*8;
    float4 h0 = *(const float4*)&Hr[0];
    float4 h1 = *(const float4*)&Hr[4];
    *(float4*)&Hr[0] = make_float4(h0.x*acc[i][0], h0.y*acc[i][1], h0.z*acc[i][2], h0.w*acc[i][3]);
    *(float4*)&Hr[4] = make_float4(h1.x*acc[i][4], h1.y*acc[i][5], h1.z*acc[i][6], h1.w*acc[i][7]);
  }
}

// ------------------------------------------------------------------
// K6: out[token] += w * (H[s]@Wdown[e] + Pd@Bd[e])
// ------------------------------------------------------------------
__global__ __launch_bounds__(256) void k_gemm_down(
    const float* __restrict__ Hbuf, const float* __restrict__ Wdown,
    const float* __restrict__ BdW, const float* __restrict__ Pd,
    const float* __restrict__ wsel,
    const int* __restrict__ perm, const int* __restrict__ cnt,
    float* __restrict__ out) {
  const int e = blockIdx.z;
  const int m = cnt[e];
  const int r0 = blockIdx.y * 128;
  if (r0 >= m) return;
  const int c0 = blockIdx.x * 128;

  __shared__ float As[16][128];
  __shared__ float Bs[16][128];
  __shared__ int slotArr[128];
  __shared__ int rowAddr[128];   // clamped slot for A loads

  const int tid = threadIdx.x;
  if (tid < 128) {
    int i = r0 + tid;
    int s = (i < m) ? perm[e*NTOK + i] : -1;
    slotArr[tid] = s;
    rowAddr[tid] = (s >= 0) ? s : 0;
  }
  __syncthreads();

  const int ty = tid >> 4, tx = tid & 15;
  const int cA = tid * 2;
  const int ar0 = cA >> 2, ak0 = (cA & 3) * 4;
  const int ar1 = (cA+1) >> 2, ak1 = ((cA+1) & 3) * 4;
  const int bk0 = cA >> 5, bc0 = (cA & 31) * 4;
  const int bk1 = (cA+1) >> 5, bc1 = ((cA+1) & 31) * 4;
  const float* Bp = Wdown + (size_t)e*FF*DD + c0;

  float acc[8][8] = {};
  for (int k0 = 0; k0 < FF; k0 += 16) {
    float4 av0 = *(const float4*)&Hbuf[(size_t)rowAddr[ar0]*FF + k0 + ak0];
    float4 av1 = *(const float4*)&Hbuf[(size_t)rowAddr[ar1]*FF + k0 + ak1];
    float4 bv0 = *(const float4*)&Bp[(size_t)(k0+bk0)*DD + bc0];
    float4 bv1 = *(const float4*)&Bp[(size_t)(k0+bk1)*DD + bc1];
    __syncthreads();
    As[ak0+0][ar0]=av0.x; As[ak0+1][ar0]=av0.y; As[ak0+2][ar0]=av0.z; As[ak0+3][ar0]=av0.w;
    As[ak1+0][ar1]=av1.x; As[ak1+1][ar1]=av1.y; As[ak1+2][ar1]=av1.z; As[ak1+3][ar1]=av1.w;
    *(float4*)&Bs[bk0][bc0] = bv0;
    *(float4*)&Bs[bk1][bc1] = bv1;
    __syncthreads();
#pragma unroll
    for (int kk = 0; kk < 16; ++kk) {
      float4 a0 = *(const float4*)&As[kk][ty*8];
      float4 a1 = *(const float4*)&As[kk][ty*8+4];
      float4 b0 = *(const float4*)&Bs[kk][tx*8];
      float4 b1v= *(const float4*)&Bs[kk][tx*8+4];
      float a[8] = {a0.x,a0.y,a0.z,a0.w,a1.x,a1.y,a1.z,a1.w};
      float b[8] = {b0.x,b0.y,b0.z,b0.w,b1v.x,b1v.y,b1v.z,b1v.w};
#pragma unroll
      for (int i = 0; i < 8; ++i)
#pragma unroll
        for (int j = 0; j < 8; ++j) acc[i][j] += a[i]*b[j];
    }
  }

  int srow[8];
#pragma unroll
  for (int i = 0; i < 8; ++i) srow[i] = slotArr[ty*8 + i];

  const float* BdE = BdW + (size_t)e*RR*DD + c0;
#pragma unroll
  for (int r = 0; r < RR; ++r) {
    float4 g0 = *(const float4*)&BdE[(size_t)r*DD + tx*8];
    float4 g1 = *(const float4*)&BdE[(size_t)r*DD + tx*8+4];
    float b[8] = {g0.x,g0.y,g0.z,g0.w,g1.x,g1.y,g1.z,g1.w};
#pragma unroll
    for (int i = 0; i < 8; ++i) {
      int s = srow[i];
      float pv = (s >= 0) ? Pd[(size_t)s*RR + r] : 0.f;
#pragma unroll
      for (int j = 0; j < 8; ++j) acc[i][j] += pv * b[j];
    }
  }

#pragma unroll
  for (int i = 0; i < 8; ++i) {
    int s = srow[i];
    if (s < 0) continue;
    int token = s >> 1;
    float w = wsel[s];
    float* op = out + (size_t)token*DD + c0 + tx*8;
#pragma unroll
    for (int j = 0; j < 8; ++j) atomicAdd(&op[j], w * acc[i][j]);
  }
}

// ------------------------------------------------------------------
extern "C" void kernel_launch(void* const* d_in, const int* in_sizes, int n_in,
                              void* d_out, int out_size, void* d_ws, size_t ws_size,
                              hipStream_t stream) {
  const float* x      = (const float*)d_in[0];
  const float* hist   = (const float*)d_in[1];
  const float* persona= (const float*)d_in[2];
  const float* W1x    = (const float*)d_in[3];
  const float* W1h    = (const float*)d_in[4];
  const float* W1p    = (const float*)d_in[5];
  const float* b1     = (const float*)d_in[6];
  const float* W2     = (const float*)d_in[7];
  const float* b2     = (const float*)d_in[8];
  const float* ln_g   = (const float*)d_in[9];
  const float* ln_b   = (const float*)d_in[10];
  const float* Wg     = (const float*)d_in[11];
  const float* bg     = (const float*)d_in[12];
  const float* Wgate  = (const float*)d_in[13];
  const float* Wup    = (const float*)d_in[14];
  const float* Wdown  = (const float*)d_in[15];
  const float* Ag     = (const float*)d_in[16];
  const float* Bg     = (const float*)d_in[17];
  const float* Au     = (const float*)d_in[18];
  const float* Bu     = (const float*)d_in[19];
  const float* Ad     = (const float*)d_in[20];
  const float* Bd     = (const float*)d_in[21];
  float* out = (float*)d_out;

  char* ws = (char*)d_ws;
  size_t off = 0;
  auto alloc = [&](size_t bytes) -> char* {
    char* p = ws + off;
    off += (bytes + 255) & ~(size_t)255;
    return p;
  };
  float* xp   = (float*)alloc(sizeof(float)*(size_t)NTOK*HID);
  float* hp   = (float*)alloc(sizeof(float)*NB*HID);
  float* pp   = (float*)alloc(sizeof(float)*EE*HID);
  float* cvec = (float*)alloc(sizeof(float)*DD);
  float* scal = (float*)alloc(sizeof(float)*64);
  float* wsel = (float*)alloc(sizeof(float)*NSLOT);
  float* Pg   = (float*)alloc(sizeof(float)*(size_t)NSLOT*RR);
  float* Pu   = (float*)alloc(sizeof(float)*(size_t)NSLOT*RR);
  float* Pd   = (float*)alloc(sizeof(float)*(size_t)NSLOT*RR);
  int*   eid  = (int*)alloc(sizeof(int)*NSLOT);
  int*   perm = (int*)alloc(sizeof(int)*(size_t)EE*NTOK);
  int*   cnt  = (int*)alloc(sizeof(int)*EE);
  float* Hbuf = (float*)alloc(sizeof(float)*(size_t)NSLOT*FF);
  (void)ws_size; (void)in_sizes; (void)n_in;

  hipMemsetAsync(cnt, 0, sizeof(int)*EE, stream);
  hipMemsetAsync(out, 0, sizeof(float)*(size_t)out_size, stream);

  k_prec<<<1, 256, 0, stream>>>(ln_g, ln_b, Wg, bg, cvec, scal);
  k_proj_small<<<EE + NB, 128, 0, stream>>>(hist, persona, W1h, W1p, b1, hp, pp);
  k_xp<<<NTOK/128, 256, 0, stream>>>(x, W1x, xp);
  k_gate<<<NTOK, 256, 0, stream>>>(xp, hp, pp, W2, b2, cvec, scal, wsel, eid, perm, cnt);
  k_lora_gu<<<NSLOT, 64, 0, stream>>>(x, Ag, Au, eid, Pg, Pu);
  dim3 ggu(FF/128, NTOK/128, EE);
  k_gemm_g<<<ggu, 256, 0, stream>>>(x, Wgate, Bg, Pg, perm, cnt, Hbuf);
  k_gemm_u<<<ggu, 256, 0, stream>>>(x, Wup, Bu, Pu, perm, cnt, Hbuf);
  k_lora_d<<<NSLOT, 64, 0, stream>>>(Hbuf, Ad, eid, Pd);
  dim3 gdn(DD/128, NTOK/128, EE);
  k_gemm_down<<<gdn, 256, 0, stream>>>(Hbuf, Wdown, Bd, Pd, wsel, perm, cnt, out);
}

// Round 3
// 2232.782 us; speedup vs baseline: 3.0451x; 3.0451x over previous
//
#include <hip/hip_runtime.h>
#include <hip/hip_bf16.h>
#include <math.h>

#define NB 4
#define SS 2048
#define NTOK (NB*SS)      // 8192
#define DD 1024
#define HH 512
#define EE 8
#define FF 2816
#define RR 16
#define HID 128
#define NSLOT (2*NTOK)    // 16384
#define LN_EPS 1e-5f

typedef unsigned short u16;
typedef __attribute__((ext_vector_type(8))) short short8v;
typedef __attribute__((ext_vector_type(4))) float f32x4v;

__device__ __forceinline__ u16 f2bf(float f) {
  __hip_bfloat16 h = __float2bfloat16(f);
  return __builtin_bit_cast(u16, h);
}
__device__ __forceinline__ float bf2f(u16 u) {
  unsigned int x = ((unsigned int)u) << 16;
  return __uint_as_float(x);
}

// ------------------------------------------------------------------
// K0a: c[d] = ln_g[d]*Wg[d]; scal[0]=sum(c); scal[1]=sum(ln_b*Wg)+bg
// ------------------------------------------------------------------
__global__ void k_prec(const float* __restrict__ ln_g, const float* __restrict__ ln_b,
                       const float* __restrict__ Wg, const float* __restrict__ bg,
                       float* __restrict__ cvec, float* __restrict__ scal) {
  __shared__ float red0[256], red1[256];
  int tid = threadIdx.x;
  float s0 = 0.f, s1 = 0.f;
  for (int d = tid; d < DD; d += 256) {
    float w = Wg[d];
    float cv = ln_g[d] * w;
    cvec[d] = cv;
    s0 += cv;
    s1 += ln_b[d] * w;
  }
  red0[tid] = s0; red1[tid] = s1;
  __syncthreads();
  for (int off = 128; off > 0; off >>= 1) {
    if (tid < off) { red0[tid] += red0[tid+off]; red1[tid] += red1[tid+off]; }
    __syncthreads();
  }
  if (tid == 0) { scal[0] = red0[0]; scal[1] = red1[0] + bg[0]; }
}

// ------------------------------------------------------------------
// K0b: pp[e][k] = persona[e]@W1p[:,k] + b1[k]; hp[b][k] = hist[b]@W1h[:,k]
// ------------------------------------------------------------------
__global__ void k_proj_small(const float* __restrict__ hist, const float* __restrict__ persona,
                             const float* __restrict__ W1h, const float* __restrict__ W1p,
                             const float* __restrict__ b1,
                             float* __restrict__ hp, float* __restrict__ pp) {
  int blk = blockIdx.x, k = threadIdx.x;   // 128 threads
  if (blk < EE) {
    int e = blk;
    float acc = b1[k];
    for (int d = 0; d < DD; ++d) acc += persona[e*DD + d] * W1p[d*HID + k];
    pp[e*HID + k] = acc;
  } else {
    int b = blk - EE;
    float acc = 0.f;
    for (int d = 0; d < HH; ++d) acc += hist[b*HH + d] * W1h[d*HID + k];
    hp[b*HID + k] = acc;
  }
}

// ------------------------------------------------------------------
// K1: xp[N,128] = x[N,1024] @ W1x[1024,128]   (fp32 tile GEMM)
// ------------------------------------------------------------------
__global__ __launch_bounds__(256) void k_xp(const float* __restrict__ x,
                                            const float* __restrict__ W1x,
                                            float* __restrict__ xp) {
  __shared__ float As[16][128];
  __shared__ float Bs[16][128];
  const int tid = threadIdx.x;
  const int r0 = blockIdx.x * 128;
  const int ty = tid >> 4, tx = tid & 15;
  const int cA = tid * 2;
  const int ar0 = cA >> 2, ak0 = (cA & 3) * 4;
  const int ar1 = (cA+1) >> 2, ak1 = ((cA+1) & 3) * 4;
  const int bk0 = cA >> 5, bc0 = (cA & 31) * 4;
  const int bk1 = (cA+1) >> 5, bc1 = ((cA+1) & 31) * 4;
  float acc[8][8] = {};
  for (int k0 = 0; k0 < DD; k0 += 16) {
    float4 av0 = *(const float4*)&x[(size_t)(r0+ar0)*DD + k0 + ak0];
    float4 av1 = *(const float4*)&x[(size_t)(r0+ar1)*DD + k0 + ak1];
    float4 bv0 = *(const float4*)&W1x[(size_t)(k0+bk0)*HID + bc0];
    float4 bv1 = *(const float4*)&W1x[(size_t)(k0+bk1)*HID + bc1];
    __syncthreads();
    As[ak0+0][ar0]=av0.x; As[ak0+1][ar0]=av0.y; As[ak0+2][ar0]=av0.z; As[ak0+3][ar0]=av0.w;
    As[ak1+0][ar1]=av1.x; As[ak1+1][ar1]=av1.y; As[ak1+2][ar1]=av1.z; As[ak1+3][ar1]=av1.w;
    *(float4*)&Bs[bk0][bc0] = bv0;
    *(float4*)&Bs[bk1][bc1] = bv1;
    __syncthreads();
#pragma unroll
    for (int kk = 0; kk < 16; ++kk) {
      float4 a0 = *(const float4*)&As[kk][ty*8];
      float4 a1 = *(const float4*)&As[kk][ty*8+4];
      float4 b0 = *(const float4*)&Bs[kk][tx*8];
      float4 b1v= *(const float4*)&Bs[kk][tx*8+4];
      float a[8] = {a0.x,a0.y,a0.z,a0.w,a1.x,a1.y,a1.z,a1.w};
      float b[8] = {b0.x,b0.y,b0.z,b0.w,b1v.x,b1v.y,b1v.z,b1v.w};
#pragma unroll
      for (int i = 0; i < 8; ++i)
#pragma unroll
        for (int j = 0; j < 8; ++j) acc[i][j] += a[i]*b[j];
    }
  }
#pragma unroll
  for (int i = 0; i < 8; ++i) {
    float* op = xp + (size_t)(r0 + ty*8 + i)*HID + tx*8;
    *(float4*)&op[0] = make_float4(acc[i][0],acc[i][1],acc[i][2],acc[i][3]);
    *(float4*)&op[4] = make_float4(acc[i][4],acc[i][5],acc[i][6],acc[i][7]);
  }
}

// ------------------------------------------------------------------
// K2: gating (fp32)
// ------------------------------------------------------------------
__global__ __launch_bounds__(256) void k_gate(const float* __restrict__ xp,
    const float* __restrict__ hp, const float* __restrict__ pp,
    const float* __restrict__ W2, const float* __restrict__ b2,
    const float* __restrict__ cvec, const float* __restrict__ scal,
    float* __restrict__ wsel, int* __restrict__ eid,
    int* __restrict__ perm, int* __restrict__ cnt) {
  __shared__ float h1s[EE*HID];
  __shared__ float red[4][EE][3];
  const int t = blockIdx.x;
  const int b = t / SS;
  const int tid = threadIdx.x;
  const int lane = tid & 63, wave = tid >> 6;

  for (int idx = tid; idx < EE*HID; idx += 256) {
    int k = idx & (HID-1);
    float v = xp[(size_t)t*HID + k] + hp[b*HID + k] + pp[idx];
    h1s[idx] = v > 0.f ? v : 0.f;
  }
  __syncthreads();

  const int d4 = tid * 4;
  float acc[EE][4] = {};
  for (int k0 = 0; k0 < HID; k0 += 4) {
    float4 w0 = *(const float4*)&W2[(size_t)(k0+0)*DD + d4];
    float4 w1 = *(const float4*)&W2[(size_t)(k0+1)*DD + d4];
    float4 w2 = *(const float4*)&W2[(size_t)(k0+2)*DD + d4];
    float4 w3 = *(const float4*)&W2[(size_t)(k0+3)*DD + d4];
#pragma unroll
    for (int e = 0; e < EE; ++e) {
      float4 h = *(const float4*)&h1s[e*HID + k0];
      acc[e][0] += h.x*w0.x + h.y*w1.x + h.z*w2.x + h.w*w3.x;
      acc[e][1] += h.x*w0.y + h.y*w1.y + h.z*w2.y + h.w*w3.y;
      acc[e][2] += h.x*w0.z + h.y*w1.z + h.z*w2.z + h.w*w3.z;
      acc[e][3] += h.x*w0.w + h.y*w1.w + h.z*w2.w + h.w*w3.w;
    }
  }

  float4 b2v = *(const float4*)&b2[d4];
  float4 cv  = *(const float4*)&cvec[d4];
  float bb[4] = {b2v.x,b2v.y,b2v.z,b2v.w};
  float cc[4] = {cv.x,cv.y,cv.z,cv.w};
#pragma unroll
  for (int e = 0; e < EE; ++e) {
    float t0=0.f, t1=0.f, t2=0.f;
#pragma unroll
    for (int q = 0; q < 4; ++q) {
      float f = acc[e][q] + bb[q];
      f = f > 0.f ? f : 0.f;
      t0 += f; t1 += f*f; t2 += f*cc[q];
    }
#pragma unroll
    for (int off = 32; off > 0; off >>= 1) {
      t0 += __shfl_xor(t0, off);
      t1 += __shfl_xor(t1, off);
      t2 += __shfl_xor(t2, off);
    }
    if (lane == 0) { red[wave][e][0]=t0; red[wave][e][1]=t1; red[wave][e][2]=t2; }
  }
  __syncthreads();

  if (tid == 0) {
    float Scsum = scal[0], Cb = scal[1];
    float logits[EE];
#pragma unroll
    for (int e = 0; e < EE; ++e) {
      float s0 = red[0][e][0]+red[1][e][0]+red[2][e][0]+red[3][e][0];
      float s1 = red[0][e][1]+red[1][e][1]+red[2][e][1]+red[3][e][1];
      float sc = red[0][e][2]+red[1][e][2]+red[2][e][2]+red[3][e][2];
      float mu = s0 * (1.f/DD);
      float var = s1 * (1.f/DD) - mu*mu;
      float rs = rsqrtf(var + LN_EPS);
      logits[e] = rs * (sc - mu*Scsum) + Cb;
    }
    float m = logits[0];
#pragma unroll
    for (int e = 1; e < EE; ++e) m = fmaxf(m, logits[e]);
    float p[EE]; float sum = 0.f;
#pragma unroll
    for (int e = 0; e < EE; ++e) { p[e] = expf(logits[e]-m); sum += p[e]; }
    float inv = 1.f / sum;
    int i1 = 0;
    for (int e = 1; e < EE; ++e) if (p[e] > p[i1]) i1 = e;
    int i2 = (i1 == 0) ? 1 : 0;
    for (int e = 0; e < EE; ++e) if (e != i1 && p[e] > p[i2]) i2 = e;
    float w1 = p[i1]*inv, w2 = p[i2]*inv;
    wsel[2*t]   = w1;  wsel[2*t+1] = w2;
    eid[2*t]    = i1;  eid[2*t+1]  = i2;
    int pos = atomicAdd(&cnt[i1], 1); perm[i1*NTOK + pos] = 2*t;
    pos     = atomicAdd(&cnt[i2], 1); perm[i2*NTOK + pos] = 2*t+1;
  }
}

// ------------------------------------------------------------------
// convert x -> bf16
// ------------------------------------------------------------------
__global__ __launch_bounds__(256) void k_cvt_x(const float* __restrict__ in,
                                               u16* __restrict__ out, int n4) {
  int i = blockIdx.x * 256 + threadIdx.x;
  if (i < n4) {
    float4 v = ((const float4*)in)[i];
    ushort4 o;
    o.x = f2bf(v.x); o.y = f2bf(v.y); o.z = f2bf(v.z); o.w = f2bf(v.w);
    ((ushort4*)out)[i] = o;
  }
}

// ------------------------------------------------------------------
// transpose+convert: in fp32 [R][C] -> out bf16 [C][R]; blockIdx.z = matrix
// ------------------------------------------------------------------
__global__ __launch_bounds__(256) void k_tr(const float* __restrict__ in,
                                            u16* __restrict__ out, int R, int C) {
  in  += (size_t)blockIdx.z * R * C;
  out += (size_t)blockIdx.z * R * C;
  __shared__ float t[64][65];
  const int tid = threadIdx.x;
  const int cx = blockIdx.x * 64, rx = blockIdx.y * 64;
  const int a  = tid >> 4;          // 0..15
  const int b4 = (tid & 15) * 4;
#pragma unroll
  for (int it = 0; it < 4; ++it) {
    int r = rx + a + it*16;
    float4 v = *(const float4*)&in[(size_t)r*C + cx + b4];
    t[a+it*16][b4+0] = v.x; t[a+it*16][b4+1] = v.y;
    t[a+it*16][b4+2] = v.z; t[a+it*16][b4+3] = v.w;
  }
  __syncthreads();
#pragma unroll
  for (int it = 0; it < 4; ++it) {
    int c = cx + a + it*16;
    ushort4 o;
    o.x = f2bf(t[b4+0][a+it*16]);
    o.y = f2bf(t[b4+1][a+it*16]);
    o.z = f2bf(t[b4+2][a+it*16]);
    o.w = f2bf(t[b4+3][a+it*16]);
    *(ushort4*)&out[(size_t)c*R + rx + b4] = o;
  }
}

// ------------------------------------------------------------------
// K3: Pg/Pu[s,r] = x[token] @ Ag/Au[e][:,r]   (fp32, 1 wave per slot)
// ------------------------------------------------------------------
__global__ __launch_bounds__(64) void k_lora_gu(const float* __restrict__ x,
    const float* __restrict__ Ag, const float* __restrict__ Au,
    const int* __restrict__ eid, float* __restrict__ Pg, float* __restrict__ Pu) {
  const int s = blockIdx.x, lane = threadIdx.x;
  const int e = eid[s];
  const int token = s >> 1;
  const int r = lane & 15, d0 = lane >> 4;
  const float* xr  = x  + (size_t)token*DD;
  const float* AgE = Ag + (size_t)e*DD*RR + r;
  const float* AuE = Au + (size_t)e*DD*RR + r;
  float g0=0.f, g1=0.f, u0=0.f, u1=0.f;
  for (int d = d0; d < DD; d += 8) {
    float x0 = xr[d], x1 = xr[d+4];
    g0 += x0 * AgE[(size_t)d*RR];     g1 += x1 * AgE[(size_t)(d+4)*RR];
    u0 += x0 * AuE[(size_t)d*RR];     u1 += x1 * AuE[(size_t)(d+4)*RR];
  }
  float g = g0+g1, u = u0+u1;
  g += __shfl_xor(g, 16); g += __shfl_xor(g, 32);
  u += __shfl_xor(u, 16); u += __shfl_xor(u, 32);
  if (lane < 16) { Pg[(size_t)s*RR + r] = g; Pu[(size_t)s*RR + r] = u; }
}

// ------------------------------------------------------------------
// K5: Pd[s,r] = H[s](bf16) @ Ad[e][:,r]
// ------------------------------------------------------------------
__global__ __launch_bounds__(64) void k_lora_d(const u16* __restrict__ Hb,
    const float* __restrict__ Ad, const int* __restrict__ eid, float* __restrict__ Pd) {
  const int s = blockIdx.x, lane = threadIdx.x;
  const int e = eid[s];
  const int r = lane & 15, d0 = lane >> 4;
  const u16* Hr  = Hb + (size_t)s*FF;
  const float* AdE = Ad + (size_t)e*FF*RR + r;
  float a0=0.f, a1=0.f;
  for (int d = d0; d < FF; d += 8) {
    a0 += bf2f(Hr[d])   * AdE[(size_t)d*RR];
    a1 += bf2f(Hr[d+4]) * AdE[(size_t)(d+4)*RR];
  }
  float a = a0+a1;
  a += __shfl_xor(a, 16); a += __shfl_xor(a, 32);
  if (lane < 16) Pd[(size_t)s*RR + r] = a;
}

// ==================================================================
// Fused gate+up MFMA GEMM:
//   g = x@Wgate + Pg@Bg ; u = x@Wup + Pu@Bu ; Hb = bf16(silu(g)*u)
// 128x128 tile, BK=32, 4 waves (2x2), mfma_f32_16x16x32_bf16.
// ==================================================================
__global__ __launch_bounds__(256) void k_mfma_gu(
    const u16* __restrict__ xb,      // [NTOK][DD] bf16
    const u16* __restrict__ WgT,     // [E][FF][DD] bf16 (transposed)
    const u16* __restrict__ WuT,
    const float* __restrict__ BgW,   // [E][16][FF] fp32
    const float* __restrict__ BuW,
    const float* __restrict__ Pg,    // [NSLOT][16] fp32
    const float* __restrict__ Pu,
    const int* __restrict__ perm, const int* __restrict__ cnt,
    u16* __restrict__ Hb)            // [NSLOT][FF] bf16
{
  const int e    = blockIdx.z;
  const int mcnt = cnt[e];
  const int r0   = blockIdx.y * 128;
  if (r0 >= mcnt) return;
  const int c0   = blockIdx.x * 128;

  __shared__ __align__(16) u16 As [4][128][8];
  __shared__ __align__(16) u16 Bsg[4][128][8];
  __shared__ __align__(16) u16 Bsu[4][128][8];
  __shared__ int slotArr[128];
  __shared__ int rowArr[128];

  const int tid = threadIdx.x;
  if (tid < 128) {
    int i = r0 + tid;
    int s = (i < mcnt) ? perm[e*NTOK + i] : -1;
    slotArr[tid] = s;
    rowArr[tid]  = (s >= 0) ? (s >> 1) : 0;
  }
  __syncthreads();

  const int lane = tid & 63;
  const int wid  = tid >> 6;
  const int wr = (wid >> 1) * 64;
  const int wc = (wid & 1) * 64;
  const int lr = lane & 15;
  const int kh = lane >> 4;

  const int srow = tid & 127;
  const int skc  = tid >> 7;          // 0/1 -> chunks {skc, skc+2}
  const size_t arow = (size_t)rowArr[srow] * DD;
  const u16* bgp = WgT + (size_t)e*FF*DD + (size_t)(c0 + srow)*DD;
  const u16* bup = WuT + (size_t)e*FF*DD + (size_t)(c0 + srow)*DD;

  f32x4v accg[4][4] = {};
  f32x4v accu[4][4] = {};

  for (int k0 = 0; k0 < DD; k0 += 32) {
    short8v av0 = *(const short8v*)(xb + arow + k0 + skc*8);
    short8v av1 = *(const short8v*)(xb + arow + k0 + skc*8 + 16);
    short8v bg0 = *(const short8v*)(bgp + k0 + skc*8);
    short8v bg1 = *(const short8v*)(bgp + k0 + skc*8 + 16);
    short8v bu0 = *(const short8v*)(bup + k0 + skc*8);
    short8v bu1 = *(const short8v*)(bup + k0 + skc*8 + 16);
    __syncthreads();
    *(short8v*)&As [skc][srow][0]   = av0;
    *(short8v*)&As [skc+2][srow][0] = av1;
    *(short8v*)&Bsg[skc][srow][0]   = bg0;
    *(short8v*)&Bsg[skc+2][srow][0] = bg1;
    *(short8v*)&Bsu[skc][srow][0]   = bu0;
    *(short8v*)&Bsu[skc+2][srow][0] = bu1;
    __syncthreads();
    short8v af[4], bg[4], bu[4];
#pragma unroll
    for (int i = 0; i < 4; ++i) af[i] = *(const short8v*)&As [kh][wr + i*16 + lr][0];
#pragma unroll
    for (int j = 0; j < 4; ++j) bg[j] = *(const short8v*)&Bsg[kh][wc + j*16 + lr][0];
#pragma unroll
    for (int j = 0; j < 4; ++j) bu[j] = *(const short8v*)&Bsu[kh][wc + j*16 + lr][0];
#pragma unroll
    for (int i = 0; i < 4; ++i)
#pragma unroll
      for (int j = 0; j < 4; ++j) {
        accg[i][j] = __builtin_amdgcn_mfma_f32_16x16x32_bf16(af[i], bg[j], accg[i][j], 0, 0, 0);
        accu[i][j] = __builtin_amdgcn_mfma_f32_16x16x32_bf16(af[i], bu[j], accu[i][j], 0, 0, 0);
      }
  }

  // ---- LoRA epilogue as one extra MFMA K-tile ----
  // As: k0..15 = Pg row, k16..31 = Pu row
  // Bsg: k0..15 = Bg,  k16..31 = 0 ; Bsu: k0..15 = 0, k16..31 = Bu
  __syncthreads();
  {
    int s = slotArr[srow];
    short8v pkg, pku, zk = {0,0,0,0,0,0,0,0};
    if (s >= 0) {
      const float* prg = Pg + (size_t)s*RR + skc*8;
      const float* pru = Pu + (size_t)s*RR + skc*8;
#pragma unroll
      for (int j = 0; j < 8; ++j) { pkg[j] = (short)f2bf(prg[j]); pku[j] = (short)f2bf(pru[j]); }
    } else { pkg = zk; pku = zk; }
    *(short8v*)&As[skc][srow][0]   = pkg;
    *(short8v*)&As[skc+2][srow][0] = pku;
    const float* lbg = BgW + (size_t)e*RR*FF + c0 + srow;
    const float* lbu = BuW + (size_t)e*RR*FF + c0 + srow;
    short8v bkg, bku;
#pragma unroll
    for (int j = 0; j < 8; ++j) {
      bkg[j] = (short)f2bf(lbg[(size_t)(skc*8+j)*FF]);
      bku[j] = (short)f2bf(lbu[(size_t)(skc*8+j)*FF]);
    }
    *(short8v*)&Bsg[skc][srow][0]   = bkg;
    *(short8v*)&Bsg[skc+2][srow][0] = zk;
    *(short8v*)&Bsu[skc][srow][0]   = zk;
    *(short8v*)&Bsu[skc+2][srow][0] = bku;
  }
  __syncthreads();
  {
    short8v af[4], bg[4], bu[4];
#pragma unroll
    for (int i = 0; i < 4; ++i) af[i] = *(const short8v*)&As [kh][wr + i*16 + lr][0];
#pragma unroll
    for (int j = 0; j < 4; ++j) bg[j] = *(const short8v*)&Bsg[kh][wc + j*16 + lr][0];
#pragma unroll
    for (int j = 0; j < 4; ++j) bu[j] = *(const short8v*)&Bsu[kh][wc + j*16 + lr][0];
#pragma unroll
    for (int i = 0; i < 4; ++i)
#pragma unroll
      for (int j = 0; j < 4; ++j) {
        accg[i][j] = __builtin_amdgcn_mfma_f32_16x16x32_bf16(af[i], bg[j], accg[i][j], 0, 0, 0);
        accu[i][j] = __builtin_amdgcn_mfma_f32_16x16x32_bf16(af[i], bu[j], accu[i][j], 0, 0, 0);
      }
  }

  // ---- epilogue: Hb = bf16(silu(g) * u) ----
#pragma unroll
  for (int i = 0; i < 4; ++i) {
#pragma unroll
    for (int q = 0; q < 4; ++q) {
      int row = wr + i*16 + kh*4 + q;
      int s = slotArr[row];
      if (s < 0) continue;
      u16* hr = Hb + (size_t)s*FF + c0;
#pragma unroll
      for (int j = 0; j < 4; ++j) {
        float g = accg[i][j][q];
        float u = accu[i][j][q];
        float sg = g / (1.f + expf(-g));
        hr[wc + j*16 + lr] = f2bf(sg * u);
      }
    }
  }
}

// ==================================================================
// Down MFMA GEMM: out[tok] += w * (Hb@Wdown + Pd@Bd)
// ==================================================================
__global__ __launch_bounds__(256) void k_mfma_down(
    const u16* __restrict__ Hb,      // [NSLOT][FF] bf16
    const u16* __restrict__ WdT,     // [E][DD][FF] bf16 (transposed)
    const float* __restrict__ BdW,   // [E][16][DD] fp32
    const float* __restrict__ Pd,    // [NSLOT][16] fp32
    const float* __restrict__ wsel,
    const int* __restrict__ perm, const int* __restrict__ cnt,
    float* __restrict__ out)
{
  const int e    = blockIdx.z;
  const int mcnt = cnt[e];
  const int r0   = blockIdx.y * 128;
  if (r0 >= mcnt) return;
  const int c0   = blockIdx.x * 128;

  __shared__ __align__(16) u16 As[4][128][8];
  __shared__ __align__(16) u16 Bs[4][128][8];
  __shared__ int slotArr[128];
  __shared__ int rowArr[128];

  const int tid = threadIdx.x;
  if (tid < 128) {
    int i = r0 + tid;
    int s = (i < mcnt) ? perm[e*NTOK + i] : -1;
    slotArr[tid] = s;
    rowArr[tid]  = (s >= 0) ? s : 0;
  }
  __syncthreads();

  const int lane = tid & 63;
  const int wid  = tid >> 6;
  const int wr = (wid >> 1) * 64;
  const int wc = (wid & 1) * 64;
  const int lr = lane & 15;
  const int kh = lane >> 4;

  const int srow = tid & 127;
  const int skc  = tid >> 7;
  const size_t arow = (size_t)rowArr[srow] * FF;
  const u16* bp = WdT + (size_t)e*DD*FF + (size_t)(c0 + srow)*FF;

  f32x4v acc[4][4] = {};

  for (int k0 = 0; k0 < FF; k0 += 32) {
    short8v av0 = *(const short8v*)(Hb + arow + k0 + skc*8);
    short8v av1 = *(const short8v*)(Hb + arow + k0 + skc*8 + 16);
    short8v bv0 = *(const short8v*)(bp + k0 + skc*8);
    short8v bv1 = *(const short8v*)(bp + k0 + skc*8 + 16);
    __syncthreads();
    *(short8v*)&As[skc][srow][0]   = av0;
    *(short8v*)&As[skc+2][srow][0] = av1;
    *(short8v*)&Bs[skc][srow][0]   = bv0;
    *(short8v*)&Bs[skc+2][srow][0] = bv1;
    __syncthreads();
    short8v af[4], bf_[4];
#pragma unroll
    for (int i = 0; i < 4; ++i) af[i]  = *(const short8v*)&As[kh][wr + i*16 + lr][0];
#pragma unroll
    for (int j = 0; j < 4; ++j) bf_[j] = *(const short8v*)&Bs[kh][wc + j*16 + lr][0];
#pragma unroll
    for (int i = 0; i < 4; ++i)
#pragma unroll
      for (int j = 0; j < 4; ++j)
        acc[i][j] = __builtin_amdgcn_mfma_f32_16x16x32_bf16(af[i], bf_[j], acc[i][j], 0, 0, 0);
  }

  // ---- LoRA epilogue tile: As k0..15 = Pd, Bs k0..15 = Bd, upper zero ----
  __syncthreads();
  {
    int s = slotArr[srow];
    short8v pk, zk = {0,0,0,0,0,0,0,0};
    if (s >= 0) {
      const float* pr = Pd + (size_t)s*RR + skc*8;
#pragma unroll
      for (int j = 0; j < 8; ++j) pk[j] = (short)f2bf(pr[j]);
    } else pk = zk;
    *(short8v*)&As[skc][srow][0]   = pk;
    *(short8v*)&As[skc+2][srow][0] = zk;
    const float* lb = BdW + (size_t)e*RR*DD + c0 + srow;
    short8v bk;
#pragma unroll
    for (int j = 0; j < 8; ++j) bk[j] = (short)f2bf(lb[(size_t)(skc*8+j)*DD]);
    *(short8v*)&Bs[skc][srow][0]   = bk;
    *(short8v*)&Bs[skc+2][srow][0] = zk;
  }
  __syncthreads();
  {
    short8v af[4], bf_[4];
#pragma unroll
    for (int i = 0; i < 4; ++i) af[i]  = *(const short8v*)&As[kh][wr + i*16 + lr][0];
#pragma unroll
    for (int j = 0; j < 4; ++j) bf_[j] = *(const short8v*)&Bs[kh][wc + j*16 + lr][0];
#pragma unroll
    for (int i = 0; i < 4; ++i)
#pragma unroll
      for (int j = 0; j < 4; ++j)
        acc[i][j] = __builtin_amdgcn_mfma_f32_16x16x32_bf16(af[i], bf_[j], acc[i][j], 0, 0, 0);
  }

  // ---- weighted atomic combine ----
#pragma unroll
  for (int i = 0; i < 4; ++i) {
#pragma unroll
    for (int q = 0; q < 4; ++q) {
      int row = wr + i*16 + kh*4 + q;
      int s = slotArr[row];
      if (s < 0) continue;
      float w = wsel[s];
      float* op = out + (size_t)(s >> 1)*DD + c0;
#pragma unroll
      for (int j = 0; j < 4; ++j)
        atomicAdd(&op[wc + j*16 + lr], w * acc[i][j][q]);
    }
  }
}

// ------------------------------------------------------------------
extern "C" void kernel_launch(void* const* d_in, const int* in_sizes, int n_in,
                              void* d_out, int out_size, void* d_ws, size_t ws_size,
                              hipStream_t stream) {
  const float* x      = (const float*)d_in[0];
  const float* hist   = (const float*)d_in[1];
  const float* persona= (const float*)d_in[2];
  const float* W1x    = (const float*)d_in[3];
  const float* W1h    = (const float*)d_in[4];
  const float* W1p    = (const float*)d_in[5];
  const float* b1     = (const float*)d_in[6];
  const float* W2     = (const float*)d_in[7];
  const float* b2     = (const float*)d_in[8];
  const float* ln_g   = (const float*)d_in[9];
  const float* ln_b   = (const float*)d_in[10];
  const float* Wg     = (const float*)d_in[11];
  const float* bg     = (const float*)d_in[12];
  const float* Wgate  = (const float*)d_in[13];
  const float* Wup    = (const float*)d_in[14];
  const float* Wdown  = (const float*)d_in[15];
  const float* Ag     = (const float*)d_in[16];
  const float* Bg     = (const float*)d_in[17];
  const float* Au     = (const float*)d_in[18];
  const float* Bu     = (const float*)d_in[19];
  const float* Ad     = (const float*)d_in[20];
  const float* Bd     = (const float*)d_in[21];
  float* out = (float*)d_out;

  char* ws = (char*)d_ws;
  size_t off = 0;
  auto alloc = [&](size_t bytes) -> char* {
    char* p = ws + off;
    off += (bytes + 255) & ~(size_t)255;
    return p;
  };
  float* xp   = (float*)alloc(sizeof(float)*(size_t)NTOK*HID);
  float* hp   = (float*)alloc(sizeof(float)*NB*HID);
  float* pp   = (float*)alloc(sizeof(float)*EE*HID);
  float* cvec = (float*)alloc(sizeof(float)*DD);
  float* scal = (float*)alloc(sizeof(float)*64);
  float* wsel = (float*)alloc(sizeof(float)*NSLOT);
  float* Pg   = (float*)alloc(sizeof(float)*(size_t)NSLOT*RR);
  float* Pu   = (float*)alloc(sizeof(float)*(size_t)NSLOT*RR);
  float* Pd   = (float*)alloc(sizeof(float)*(size_t)NSLOT*RR);
  int*   eid  = (int*)alloc(sizeof(int)*NSLOT);
  int*   perm = (int*)alloc(sizeof(int)*(size_t)EE*NTOK);
  int*   cnt  = (int*)alloc(sizeof(int)*EE);
  u16*   xb   = (u16*)alloc(sizeof(u16)*(size_t)NTOK*DD);
  u16*   WgT  = (u16*)alloc(sizeof(u16)*(size_t)EE*FF*DD);   // aliased by WdT later
  u16*   WuT  = (u16*)alloc(sizeof(u16)*(size_t)EE*FF*DD);
  u16*   Hb   = (u16*)alloc(sizeof(u16)*(size_t)NSLOT*FF);
  u16*   WdT  = WgT;   // WgT dead after k_mfma_gu; WdT written after it (stream-ordered)
  (void)ws_size; (void)in_sizes; (void)n_in;

  hipMemsetAsync(cnt, 0, sizeof(int)*EE, stream);
  hipMemsetAsync(out, 0, sizeof(float)*(size_t)out_size, stream);

  // gating (fp32)
  k_prec<<<1, 256, 0, stream>>>(ln_g, ln_b, Wg, bg, cvec, scal);
  k_proj_small<<<EE + NB, 128, 0, stream>>>(hist, persona, W1h, W1p, b1, hp, pp);
  k_xp<<<NTOK/128, 256, 0, stream>>>(x, W1x, xp);
  k_gate<<<NTOK, 256, 0, stream>>>(xp, hp, pp, W2, b2, cvec, scal, wsel, eid, perm, cnt);

  // bf16 prepass (gate/up weights + x)
  k_cvt_x<<<(NTOK*DD/4 + 255)/256, 256, 0, stream>>>(x, xb, NTOK*DD/4);
  k_tr<<<dim3(FF/64, DD/64, EE), 256, 0, stream>>>(Wgate, WgT, DD, FF);
  k_tr<<<dim3(FF/64, DD/64, EE), 256, 0, stream>>>(Wup,   WuT, DD, FF);

  // LoRA projections (fp32)
  k_lora_gu<<<NSLOT, 64, 0, stream>>>(x, Ag, Au, eid, Pg, Pu);

  // expert GEMMs (bf16 MFMA)
  k_mfma_gu<<<dim3(FF/128, NTOK/128, EE), 256, 0, stream>>>(
      xb, WgT, WuT, Bg, Bu, Pg, Pu, perm, cnt, Hb);

  // Wdown transpose AFTER gu-GEMM so WdT can alias WgT (saves ~46 MB peak ws)
  k_tr<<<dim3(DD/64, FF/64, EE), 256, 0, stream>>>(Wdown, WdT, FF, DD);

  k_lora_d<<<NSLOT, 64, 0, stream>>>(Hb, Ad, eid, Pd);
  k_mfma_down<<<dim3(DD/128, NTOK/128, EE), 256, 0, stream>>>(
      Hb, WdT, Bd, Pd, wsel, perm, cnt, out);
}